// Round 1
// baseline (1436.428 us; speedup 1.0000x reference)
//
#include <hip/hip_runtime.h>
#include <math.h>

#define F1 100
#define F2 200

__device__ __forceinline__ float siluf(float v) {
    return v / (1.0f + expf(-v));
}

__global__ void k_count_deg(const int* __restrict__ dst, int E, int* __restrict__ deg) {
    int i = blockIdx.x * blockDim.x + threadIdx.x;
    if (i < E) atomicAdd(&deg[dst[i]], 1);
}

__global__ void k_count_batch(const int* __restrict__ batch, int N, int* __restrict__ counts) {
    int i = blockIdx.x * blockDim.x + threadIdx.x;
    if (i < N) atomicAdd(&counts[batch[i]], 1);
}

__global__ void k_dinv_self(const int* __restrict__ deg, const float* __restrict__ x, int N,
                            float* __restrict__ dinv, float* __restrict__ aggx) {
    int i = blockIdx.x * blockDim.x + threadIdx.x;
    if (i < N) {
        float d = 1.0f / sqrtf((float)deg[i] + 1.0f);
        dinv[i] = d;
        aggx[i] = x[i] * d * d;   // self-loop message, layer 1 (scalar feature)
    }
}

#define SCAN_T 1024
__global__ void k_scan(const int* __restrict__ deg, int N, int* __restrict__ off) {
    __shared__ int part[SCAN_T];
    int t = threadIdx.x;
    int chunk = (N + SCAN_T - 1) / SCAN_T;
    int beg = t * chunk;
    int end = min(beg + chunk, N);
    int s = 0;
    for (int i = beg; i < end; ++i) s += deg[i];
    part[t] = s;
    __syncthreads();
    for (int ofs = 1; ofs < SCAN_T; ofs <<= 1) {
        int v = (t >= ofs) ? part[t - ofs] : 0;
        __syncthreads();
        part[t] += v;
        __syncthreads();
    }
    int run = (t == 0) ? 0 : part[t - 1];
    for (int i = beg; i < end; ++i) { off[i] = run; run += deg[i]; }
    if (t == SCAN_T - 1) off[N] = part[SCAN_T - 1];
}

__global__ void k_fill(const int* __restrict__ src, const int* __restrict__ dst, int E,
                       const int* __restrict__ off, int* __restrict__ cursor, int* __restrict__ nbr) {
    int e = blockIdx.x * blockDim.x + threadIdx.x;
    if (e < E) {
        int d = dst[e];
        int p = atomicAdd(&cursor[d], 1);
        nbr[off[d] + p] = src[e];
    }
}

__global__ void k_aggx_edges(const int* __restrict__ src, const int* __restrict__ dst, int E,
                             const float* __restrict__ x, const float* __restrict__ dinv,
                             float* __restrict__ aggx) {
    int e = blockIdx.x * blockDim.x + threadIdx.x;
    if (e < E) {
        int s = src[e], d = dst[e];
        atomicAdd(&aggx[d], x[s] * dinv[s] * dinv[d]);
    }
}

// Layer-2 aggregation with on-the-fly recompute of layer-1 output rows from the
// scalar aggx. One wave per node; lanes own features (j=lane, j=lane+64).
__global__ __launch_bounds__(256) void k_aggh(
    const int* __restrict__ off, const int* __restrict__ nbr,
    const float* __restrict__ aggx, const float* __restrict__ dinv,
    const float* __restrict__ W1, const float* __restrict__ b1,
    int N, float* __restrict__ aggh)
{
    int wave = threadIdx.x >> 6;
    int lane = threadIdx.x & 63;
    int n = blockIdx.x * 4 + wave;
    if (n >= N) return;
    int ja = lane;
    int jb = lane + 64;
    float w1a = (ja < F1) ? W1[ja] : 0.0f;
    float b1a = (ja < F1) ? b1[ja] : 0.0f;
    float w1b = (jb < F1) ? W1[jb] : 0.0f;
    float b1b = (jb < F1) ? b1[jb] : 0.0f;
    float d0 = dinv[n];
    float a0 = aggx[n];
    float accA = siluf(fmaf(a0, w1a, b1a)) * (d0 * d0);   // self-loop term
    float accB = siluf(fmaf(a0, w1b, b1b)) * (d0 * d0);
    int beg = off[n], end = off[n + 1];
    for (int t = beg; t < end; t += 64) {
        int cnt = min(64, end - t);
        float sa = 0.0f, sw = 0.0f;
        if (lane < cnt) {
            int s = nbr[t + lane];
            sa = aggx[s];
            sw = dinv[s] * d0;
        }
        for (int i = 0; i < cnt; ++i) {
            float ai = __shfl(sa, i);
            float wi = __shfl(sw, i);
            accA += wi * siluf(fmaf(ai, w1a, b1a));
            accB += wi * siluf(fmaf(ai, w1b, b1b));
        }
    }
    if (ja < F1) aggh[(size_t)n * F1 + ja] = accA;
    if (jb < F1) aggh[(size_t)n * F1 + jb] = accB;
}

// Fused: h2 = silu(aggh @ W2 + b2), pooled[batch[n]] += h2 (double accumulation).
// Block = 256 threads, thread owns output feature m (<200); 64 nodes/block.
#define NPB 64
#define STAGE 8
__global__ __launch_bounds__(256) void k_h2_pool(
    const float* __restrict__ aggh, const float* __restrict__ W2, const float* __restrict__ b2,
    const int* __restrict__ batch, int N, double* __restrict__ pooled)
{
    __shared__ float sh[STAGE][F1];
    __shared__ int sbatch[NPB];
    int tid = threadIdx.x;
    int base = blockIdx.x * NPB;
    int m = tid;
    float w2c[F1];
    if (m < F2) {
        #pragma unroll
        for (int j = 0; j < F1; ++j) w2c[j] = W2[j * F2 + m];
    }
    float bb = (m < F2) ? b2[m] : 0.0f;
    if (tid < NPB && base + tid < N) sbatch[tid] = batch[base + tid];
    __syncthreads();
    double pl = 0.0;
    int gcur = -1;
    for (int t0 = 0; t0 < NPB; t0 += STAGE) {
        for (int idx = tid; idx < STAGE * F1; idx += 256) {
            int r = idx / F1, c = idx % F1;
            int n = base + t0 + r;
            sh[r][c] = (n < N) ? aggh[(size_t)n * F1 + c] : 0.0f;
        }
        __syncthreads();
        for (int r = 0; r < STAGE; ++r) {
            int n = base + t0 + r;
            if (n >= N) break;
            int g = sbatch[t0 + r];
            if (g != gcur) {
                if (gcur >= 0 && m < F2) atomicAdd(&pooled[(size_t)gcur * F2 + m], pl);
                pl = 0.0;
                gcur = g;
            }
            if (m < F2) {
                float acc = bb;
                #pragma unroll
                for (int j = 0; j < F1; ++j) acc = fmaf(sh[r][j], w2c[j], acc);
                pl += (double)siluf(acc);
            }
        }
        __syncthreads();
    }
    if (gcur >= 0 && m < F2) atomicAdd(&pooled[(size_t)gcur * F2 + m], pl);
}

// Head MLP on [G,200] in double precision. Single block.
__global__ __launch_bounds__(256) void k_head(
    const double* __restrict__ pooled, const int* __restrict__ counts,
    const float* __restrict__ Wl1, const float* __restrict__ bl1,
    const float* __restrict__ Wl2, const float* __restrict__ bl2,
    int G, float* __restrict__ out)
{
    __shared__ double t1[64 * 100];
    int tid = threadIdx.x;
    for (int idx = tid; idx < G * 100; idx += blockDim.x) {
        int g = idx / 100;
        int k = idx % 100;
        double icnt = 1.0 / (double)max(counts[g], 1);
        double acc = (double)bl1[k];
        for (int m = 0; m < F2; ++m) {
            acc += (pooled[(size_t)g * F2 + m] * icnt) * (double)Wl1[m * 100 + k];
        }
        t1[g * 100 + k] = acc / (1.0 + exp(-acc));
    }
    __syncthreads();
    for (int g = tid; g < G; g += blockDim.x) {
        double acc = (double)bl2[0];
        for (int k = 0; k < 100; ++k) acc += t1[g * 100 + k] * (double)Wl2[k];
        out[g] = (float)acc;
    }
}

extern "C" void kernel_launch(void* const* d_in, const int* in_sizes, int n_in,
                              void* d_out, int out_size, void* d_ws, size_t ws_size,
                              hipStream_t stream)
{
    const float* x   = (const float*)d_in[0];
    const int*   src = (const int*)d_in[1];
    const int*   dst = (const int*)d_in[2];
    const int*   batch = (const int*)d_in[3];
    const float* W1  = (const float*)d_in[4];
    const float* b1  = (const float*)d_in[5];
    const float* W2  = (const float*)d_in[6];
    const float* b2  = (const float*)d_in[7];
    const float* Wl1 = (const float*)d_in[8];
    const float* bl1 = (const float*)d_in[9];
    const float* Wl2 = (const float*)d_in[10];
    const float* bl2 = (const float*)d_in[11];
    int N = in_sizes[0];
    int E = in_sizes[1];
    int G = out_size;
    float* out = (float*)d_out;

    char* ws = (char*)d_ws;
    size_t o = 0;
    auto alloc = [&](size_t bytes) -> void* {
        o = (o + 255) & ~(size_t)255;
        void* p = ws + o;
        o += bytes;
        return p;
    };
    int*    deg    = (int*)alloc((size_t)N * 4);
    int*    cursor = (int*)alloc((size_t)N * 4);
    int*    off    = (int*)alloc((size_t)(N + 1) * 4);
    int*    nbr    = (int*)alloc((size_t)E * 4);
    float*  dinv   = (float*)alloc((size_t)N * 4);
    float*  aggx   = (float*)alloc((size_t)N * 4);
    float*  aggh   = (float*)alloc((size_t)N * F1 * 4);
    double* pooled = (double*)alloc((size_t)G * F2 * 8);
    int*    counts = (int*)alloc((size_t)G * 4);

    hipMemsetAsync(deg, 0, (size_t)N * 4, stream);
    hipMemsetAsync(cursor, 0, (size_t)N * 4, stream);
    hipMemsetAsync(counts, 0, (size_t)G * 4, stream);
    hipMemsetAsync(pooled, 0, (size_t)G * F2 * 8, stream);

    int tE = (E + 255) / 256;
    int tN = (N + 255) / 256;
    k_count_deg<<<tE, 256, 0, stream>>>(dst, E, deg);
    k_count_batch<<<tN, 256, 0, stream>>>(batch, N, counts);
    k_dinv_self<<<tN, 256, 0, stream>>>(deg, x, N, dinv, aggx);
    k_scan<<<1, SCAN_T, 0, stream>>>(deg, N, off);
    k_fill<<<tE, 256, 0, stream>>>(src, dst, E, off, cursor, nbr);
    k_aggx_edges<<<tE, 256, 0, stream>>>(src, dst, E, x, dinv, aggx);
    k_aggh<<<(N + 3) / 4, 256, 0, stream>>>(off, nbr, aggx, dinv, W1, b1, N, aggh);
    k_h2_pool<<<(N + NPB - 1) / NPB, 256, 0, stream>>>(aggh, W2, b2, batch, N, pooled);
    k_head<<<1, 256, 0, stream>>>(pooled, counts, Wl1, bl1, Wl2, bl2, G, out);
}

// Round 2
// 857.316 us; speedup vs baseline: 1.6755x; 1.6755x over previous
//
#include <hip/hip_runtime.h>
#include <math.h>

#define F1 100
#define F2 200

__device__ __forceinline__ float siluf(float v) {
    return v / (1.0f + expf(-v));
}

__global__ void k_count_deg(const int* __restrict__ dst, int E, int* __restrict__ deg) {
    int i = blockIdx.x * blockDim.x + threadIdx.x;
    if (i < E) atomicAdd(&deg[dst[i]], 1);
}

// batch is sorted: counts via binary-searched boundaries, no atomics.
__global__ void k_batch_bounds(const int* __restrict__ batch, int N, int G,
                               int* __restrict__ starts, int* __restrict__ counts) {
    int t = threadIdx.x;
    if (t <= G) {
        int lo = 0, hi = N;
        while (lo < hi) {
            int mid = (lo + hi) >> 1;
            if (batch[mid] < t) lo = mid + 1; else hi = mid;
        }
        starts[t] = lo;
    }
    __syncthreads();
    if (t < G) counts[t] = starts[t + 1] - starts[t];
}

__global__ void k_dinv_self(const int* __restrict__ deg, const float* __restrict__ x, int N,
                            float* __restrict__ dinv, float* __restrict__ aggx) {
    int i = blockIdx.x * blockDim.x + threadIdx.x;
    if (i < N) {
        float d = 1.0f / sqrtf((float)deg[i] + 1.0f);
        dinv[i] = d;
        aggx[i] = x[i] * d * d;   // self-loop message, layer 1 (scalar feature)
    }
}

#define SCAN_T 1024
__global__ void k_scan(const int* __restrict__ deg, int N, int* __restrict__ off) {
    __shared__ int part[SCAN_T];
    int t = threadIdx.x;
    int chunk = (N + SCAN_T - 1) / SCAN_T;
    int beg = t * chunk;
    int end = min(beg + chunk, N);
    int s = 0;
    for (int i = beg; i < end; ++i) s += deg[i];
    part[t] = s;
    __syncthreads();
    for (int ofs = 1; ofs < SCAN_T; ofs <<= 1) {
        int v = (t >= ofs) ? part[t - ofs] : 0;
        __syncthreads();
        part[t] += v;
        __syncthreads();
    }
    int run = (t == 0) ? 0 : part[t - 1];
    for (int i = beg; i < end; ++i) { off[i] = run; run += deg[i]; }
    if (t == SCAN_T - 1) off[N] = part[SCAN_T - 1];
}

// Fused CSR fill + scalar layer-1 edge aggregation (single pass over src/dst).
__global__ void k_fill_agg(const int* __restrict__ src, const int* __restrict__ dst, int E,
                           const int* __restrict__ off, int* __restrict__ cursor,
                           int* __restrict__ nbr,
                           const float* __restrict__ x, const float* __restrict__ dinv,
                           float* __restrict__ aggx) {
    int e = blockIdx.x * blockDim.x + threadIdx.x;
    if (e < E) {
        int s = src[e], d = dst[e];
        int p = atomicAdd(&cursor[d], 1);
        nbr[off[d] + p] = s;
        atomicAdd(&aggx[d], x[s] * dinv[s] * dinv[d]);
    }
}

// Layer-2 aggregation with on-the-fly recompute of layer-1 output rows from the
// scalar aggx. One wave per node; lanes own features (j=lane, j=lane+64).
__global__ __launch_bounds__(256) void k_aggh(
    const int* __restrict__ off, const int* __restrict__ nbr,
    const float* __restrict__ aggx, const float* __restrict__ dinv,
    const float* __restrict__ W1, const float* __restrict__ b1,
    int N, float* __restrict__ aggh)
{
    int wave = threadIdx.x >> 6;
    int lane = threadIdx.x & 63;
    int n = blockIdx.x * 4 + wave;
    if (n >= N) return;
    int ja = lane;
    int jb = lane + 64;
    float w1a = (ja < F1) ? W1[ja] : 0.0f;
    float b1a = (ja < F1) ? b1[ja] : 0.0f;
    float w1b = (jb < F1) ? W1[jb] : 0.0f;
    float b1b = (jb < F1) ? b1[jb] : 0.0f;
    float d0 = dinv[n];
    float a0 = aggx[n];
    float accA = siluf(fmaf(a0, w1a, b1a)) * (d0 * d0);   // self-loop term
    float accB = siluf(fmaf(a0, w1b, b1b)) * (d0 * d0);
    int beg = off[n], end = off[n + 1];
    for (int t = beg; t < end; t += 64) {
        int cnt = min(64, end - t);
        float sa = 0.0f, sw = 0.0f;
        if (lane < cnt) {
            int s = nbr[t + lane];
            sa = aggx[s];
            sw = dinv[s] * d0;
        }
        for (int i = 0; i < cnt; ++i) {
            float ai = __shfl(sa, i);
            float wi = __shfl(sw, i);
            accA += wi * siluf(fmaf(ai, w1a, b1a));
            accB += wi * siluf(fmaf(ai, w1b, b1b));
        }
    }
    if (ja < F1) aggh[(size_t)n * F1 + ja] = accA;
    if (jb < F1) aggh[(size_t)n * F1 + jb] = accB;
}

// Fused: h2 = silu(aggh @ W2 + b2), pooled[batch[n]] += h2 (double accumulation).
// Block = 256 threads, thread owns output feature m (<200); 64 nodes/block.
#define NPB 64
#define STAGE 8
__global__ __launch_bounds__(256) void k_h2_pool(
    const float* __restrict__ aggh, const float* __restrict__ W2, const float* __restrict__ b2,
    const int* __restrict__ batch, int N, double* __restrict__ pooled)
{
    __shared__ float sh[STAGE][F1];
    __shared__ int sbatch[NPB];
    int tid = threadIdx.x;
    int base = blockIdx.x * NPB;
    int m = tid;
    float w2c[F1];
    if (m < F2) {
        #pragma unroll
        for (int j = 0; j < F1; ++j) w2c[j] = W2[j * F2 + m];
    }
    float bb = (m < F2) ? b2[m] : 0.0f;
    if (tid < NPB && base + tid < N) sbatch[tid] = batch[base + tid];
    __syncthreads();
    double pl = 0.0;
    int gcur = -1;
    for (int t0 = 0; t0 < NPB; t0 += STAGE) {
        for (int idx = tid; idx < STAGE * F1; idx += 256) {
            int r = idx / F1, c = idx % F1;
            int n = base + t0 + r;
            sh[r][c] = (n < N) ? aggh[(size_t)n * F1 + c] : 0.0f;
        }
        __syncthreads();
        for (int r = 0; r < STAGE; ++r) {
            int n = base + t0 + r;
            if (n >= N) break;
            int g = sbatch[t0 + r];
            if (g != gcur) {
                if (gcur >= 0 && m < F2) atomicAdd(&pooled[(size_t)gcur * F2 + m], pl);
                pl = 0.0;
                gcur = g;
            }
            if (m < F2) {
                float acc = bb;
                #pragma unroll
                for (int j = 0; j < F1; ++j) acc = fmaf(sh[r][j], w2c[j], acc);
                pl += (double)siluf(acc);
            }
        }
        __syncthreads();
    }
    if (gcur >= 0 && m < F2) atomicAdd(&pooled[(size_t)gcur * F2 + m], pl);
}

// Head MLP on [G,200] in double precision. Single block.
__global__ __launch_bounds__(256) void k_head(
    const double* __restrict__ pooled, const int* __restrict__ counts,
    const float* __restrict__ Wl1, const float* __restrict__ bl1,
    const float* __restrict__ Wl2, const float* __restrict__ bl2,
    int G, float* __restrict__ out)
{
    __shared__ double t1[64 * 100];
    int tid = threadIdx.x;
    for (int idx = tid; idx < G * 100; idx += blockDim.x) {
        int g = idx / 100;
        int k = idx % 100;
        double icnt = 1.0 / (double)max(counts[g], 1);
        double acc = (double)bl1[k];
        for (int m = 0; m < F2; ++m) {
            acc += (pooled[(size_t)g * F2 + m] * icnt) * (double)Wl1[m * 100 + k];
        }
        t1[g * 100 + k] = acc / (1.0 + exp(-acc));
    }
    __syncthreads();
    for (int g = tid; g < G; g += blockDim.x) {
        double acc = (double)bl2[0];
        for (int k = 0; k < 100; ++k) acc += t1[g * 100 + k] * (double)Wl2[k];
        out[g] = (float)acc;
    }
}

extern "C" void kernel_launch(void* const* d_in, const int* in_sizes, int n_in,
                              void* d_out, int out_size, void* d_ws, size_t ws_size,
                              hipStream_t stream)
{
    const float* x   = (const float*)d_in[0];
    const int*   src = (const int*)d_in[1];
    const int*   dst = (const int*)d_in[2];
    const int*   batch = (const int*)d_in[3];
    const float* W1  = (const float*)d_in[4];
    const float* b1  = (const float*)d_in[5];
    const float* W2  = (const float*)d_in[6];
    const float* b2  = (const float*)d_in[7];
    const float* Wl1 = (const float*)d_in[8];
    const float* bl1 = (const float*)d_in[9];
    const float* Wl2 = (const float*)d_in[10];
    const float* bl2 = (const float*)d_in[11];
    int N = in_sizes[0];
    int E = in_sizes[1];
    int G = out_size;
    float* out = (float*)d_out;

    char* ws = (char*)d_ws;
    size_t o = 0;
    auto alloc = [&](size_t bytes) -> void* {
        o = (o + 255) & ~(size_t)255;
        void* p = ws + o;
        o += bytes;
        return p;
    };
    int*    deg    = (int*)alloc((size_t)N * 4);
    int*    cursor = (int*)alloc((size_t)N * 4);
    int*    off    = (int*)alloc((size_t)(N + 1) * 4);
    int*    nbr    = (int*)alloc((size_t)E * 4);
    float*  dinv   = (float*)alloc((size_t)N * 4);
    float*  aggx   = (float*)alloc((size_t)N * 4);
    float*  aggh   = (float*)alloc((size_t)N * F1 * 4);
    double* pooled = (double*)alloc((size_t)G * F2 * 8);
    int*    counts = (int*)alloc((size_t)G * 4);
    int*    starts = (int*)alloc((size_t)(G + 1) * 4);

    hipMemsetAsync(deg, 0, (size_t)N * 4, stream);
    hipMemsetAsync(cursor, 0, (size_t)N * 4, stream);
    hipMemsetAsync(pooled, 0, (size_t)G * F2 * 8, stream);

    int tE = (E + 255) / 256;
    int tN = (N + 255) / 256;
    k_count_deg<<<tE, 256, 0, stream>>>(dst, E, deg);
    k_batch_bounds<<<1, 128, 0, stream>>>(batch, N, G, starts, counts);
    k_dinv_self<<<tN, 256, 0, stream>>>(deg, x, N, dinv, aggx);
    k_scan<<<1, SCAN_T, 0, stream>>>(deg, N, off);
    k_fill_agg<<<tE, 256, 0, stream>>>(src, dst, E, off, cursor, nbr, x, dinv, aggx);
    k_aggh<<<(N + 3) / 4, 256, 0, stream>>>(off, nbr, aggx, dinv, W1, b1, N, aggh);
    k_h2_pool<<<(N + NPB - 1) / NPB, 256, 0, stream>>>(aggh, W2, b2, batch, N, pooled);
    k_head<<<1, 256, 0, stream>>>(pooled, counts, Wl1, bl1, Wl2, bl2, G, out);
}

// Round 3
// 673.554 us; speedup vs baseline: 2.1326x; 1.2728x over previous
//
#include <hip/hip_runtime.h>
#include <math.h>

#define F1 100
#define F2 200

__device__ __forceinline__ float siluf(float v) {
    return v / (1.0f + expf(-v));
}

__global__ void k_count_deg(const int* __restrict__ dst, int E, int* __restrict__ deg) {
    int i = blockIdx.x * blockDim.x + threadIdx.x;
    if (i < E) atomicAdd(&deg[dst[i]], 1);
}

// batch is sorted: counts via binary-searched boundaries, no atomics.
__global__ void k_batch_bounds(const int* __restrict__ batch, int N, int G,
                               int* __restrict__ starts, int* __restrict__ counts) {
    int t = threadIdx.x;
    if (t <= G) {
        int lo = 0, hi = N;
        while (lo < hi) {
            int mid = (lo + hi) >> 1;
            if (batch[mid] < t) lo = mid + 1; else hi = mid;
        }
        starts[t] = lo;
    }
    __syncthreads();
    if (t < G) counts[t] = starts[t + 1] - starts[t];
}

__global__ void k_dinv_self(const int* __restrict__ deg, const float* __restrict__ x, int N,
                            float* __restrict__ dinv, float* __restrict__ aggx) {
    int i = blockIdx.x * blockDim.x + threadIdx.x;
    if (i < N) {
        float d = 1.0f / sqrtf((float)deg[i] + 1.0f);
        dinv[i] = d;
        aggx[i] = x[i] * d * d;   // self-loop message, layer 1 (scalar feature)
    }
}

#define SCAN_T 1024
__global__ void k_scan(const int* __restrict__ deg, int N, int* __restrict__ off) {
    __shared__ int part[SCAN_T];
    int t = threadIdx.x;
    int chunk = (N + SCAN_T - 1) / SCAN_T;
    int beg = t * chunk;
    int end = min(beg + chunk, N);
    int s = 0;
    for (int i = beg; i < end; ++i) s += deg[i];
    part[t] = s;
    __syncthreads();
    for (int ofs = 1; ofs < SCAN_T; ofs <<= 1) {
        int v = (t >= ofs) ? part[t - ofs] : 0;
        __syncthreads();
        part[t] += v;
        __syncthreads();
    }
    int run = (t == 0) ? 0 : part[t - 1];
    for (int i = beg; i < end; ++i) { off[i] = run; run += deg[i]; }
    if (t == SCAN_T - 1) off[N] = part[SCAN_T - 1];
}

// Fused CSR fill + scalar layer-1 edge aggregation (single pass over src/dst).
__global__ void k_fill_agg(const int* __restrict__ src, const int* __restrict__ dst, int E,
                           const int* __restrict__ off, int* __restrict__ cursor,
                           int* __restrict__ nbr,
                           const float* __restrict__ x, const float* __restrict__ dinv,
                           float* __restrict__ aggx) {
    int e = blockIdx.x * blockDim.x + threadIdx.x;
    if (e < E) {
        int s = src[e], d = dst[e];
        int p = atomicAdd(&cursor[d], 1);
        nbr[off[d] + p] = s;
        atomicAdd(&aggx[d], x[s] * dinv[s] * dinv[d]);
    }
}

// Layer-2 aggregation with on-the-fly recompute of layer-1 output rows from the
// scalar aggx. One wave per node; lanes own features (j=lane, j=lane+64).
__global__ __launch_bounds__(256) void k_aggh(
    const int* __restrict__ off, const int* __restrict__ nbr,
    const float* __restrict__ aggx, const float* __restrict__ dinv,
    const float* __restrict__ W1, const float* __restrict__ b1,
    int N, float* __restrict__ aggh)
{
    int wave = threadIdx.x >> 6;
    int lane = threadIdx.x & 63;
    int n = blockIdx.x * 4 + wave;
    if (n >= N) return;
    int ja = lane;
    int jb = lane + 64;
    float w1a = (ja < F1) ? W1[ja] : 0.0f;
    float b1a = (ja < F1) ? b1[ja] : 0.0f;
    float w1b = (jb < F1) ? W1[jb] : 0.0f;
    float b1b = (jb < F1) ? b1[jb] : 0.0f;
    float d0 = dinv[n];
    float a0 = aggx[n];
    float accA = siluf(fmaf(a0, w1a, b1a)) * (d0 * d0);   // self-loop term
    float accB = siluf(fmaf(a0, w1b, b1b)) * (d0 * d0);
    int beg = off[n], end = off[n + 1];
    for (int t = beg; t < end; t += 64) {
        int cnt = min(64, end - t);
        float sa = 0.0f, sw = 0.0f;
        if (lane < cnt) {
            int s = nbr[t + lane];
            sa = aggx[s];
            sw = dinv[s] * d0;
        }
        for (int i = 0; i < cnt; ++i) {
            float ai = __shfl(sa, i);
            float wi = __shfl(sw, i);
            accA += wi * siluf(fmaf(ai, w1a, b1a));
            accB += wi * siluf(fmaf(ai, w1b, b1b));
        }
    }
    if (ja < F1) aggh[(size_t)n * F1 + ja] = accA;
    if (jb < F1) aggh[(size_t)n * F1 + jb] = accB;
}

// Fused: h2 = silu(aggh @ W2 + b2), pooled[batch[n]] += h2 (double accumulation).
// Block = 256 threads, thread owns output feature m (<200); 64 nodes/block.
#define NPB 64
#define STAGE 8
__global__ __launch_bounds__(256) void k_h2_pool(
    const float* __restrict__ aggh, const float* __restrict__ W2, const float* __restrict__ b2,
    const int* __restrict__ batch, int N, double* __restrict__ pooled)
{
    __shared__ float sh[STAGE][F1];
    __shared__ int sbatch[NPB];
    int tid = threadIdx.x;
    int base = blockIdx.x * NPB;
    int m = tid;
    float w2c[F1];
    if (m < F2) {
        #pragma unroll
        for (int j = 0; j < F1; ++j) w2c[j] = W2[j * F2 + m];
    }
    float bb = (m < F2) ? b2[m] : 0.0f;
    if (tid < NPB && base + tid < N) sbatch[tid] = batch[base + tid];
    __syncthreads();
    double pl = 0.0;
    int gcur = -1;
    for (int t0 = 0; t0 < NPB; t0 += STAGE) {
        for (int idx = tid; idx < STAGE * F1; idx += 256) {
            int r = idx / F1, c = idx % F1;
            int n = base + t0 + r;
            sh[r][c] = (n < N) ? aggh[(size_t)n * F1 + c] : 0.0f;
        }
        __syncthreads();
        for (int r = 0; r < STAGE; ++r) {
            int n = base + t0 + r;
            if (n >= N) break;
            int g = sbatch[t0 + r];
            if (g != gcur) {
                if (gcur >= 0 && m < F2) atomicAdd(&pooled[(size_t)gcur * F2 + m], pl);
                pl = 0.0;
                gcur = g;
            }
            if (m < F2) {
                float acc = bb;
                #pragma unroll
                for (int j = 0; j < F1; ++j) acc = fmaf(sh[r][j], w2c[j], acc);
                pl += (double)siluf(acc);
            }
        }
        __syncthreads();
    }
    if (gcur >= 0 && m < F2) atomicAdd(&pooled[(size_t)gcur * F2 + m], pl);
}

// Head MLP: one block per graph. Stage pooled row in LDS; Wl1 reads coalesced
// across tid; double precision throughout (output cancels to ~2e-5).
__global__ __launch_bounds__(256) void k_head(
    const double* __restrict__ pooled, const int* __restrict__ counts,
    const float* __restrict__ Wl1, const float* __restrict__ bl1,
    const float* __restrict__ Wl2, const float* __restrict__ bl2,
    float* __restrict__ out)
{
    int g = blockIdx.x;
    int tid = threadIdx.x;
    __shared__ double sp[F2];
    __shared__ double red[256];
    double icnt = 1.0 / (double)max(counts[g], 1);
    for (int m = tid; m < F2; m += 256) sp[m] = pooled[(size_t)g * F2 + m] * icnt;
    __syncthreads();
    double part = 0.0;
    if (tid < 100) {
        double acc = (double)bl1[tid];
        #pragma unroll 4
        for (int m = 0; m < F2; ++m) acc += sp[m] * (double)Wl1[m * 100 + tid];
        double t1 = acc / (1.0 + exp(-acc));
        part = t1 * (double)Wl2[tid];
    }
    red[tid] = part;
    __syncthreads();
    for (int s = 128; s > 0; s >>= 1) {
        if (tid < s) red[tid] += red[tid + s];
        __syncthreads();
    }
    if (tid == 0) out[g] = (float)(red[0] + (double)bl2[0]);
}

extern "C" void kernel_launch(void* const* d_in, const int* in_sizes, int n_in,
                              void* d_out, int out_size, void* d_ws, size_t ws_size,
                              hipStream_t stream)
{
    const float* x   = (const float*)d_in[0];
    const int*   src = (const int*)d_in[1];
    const int*   dst = (const int*)d_in[2];
    const int*   batch = (const int*)d_in[3];
    const float* W1  = (const float*)d_in[4];
    const float* b1  = (const float*)d_in[5];
    const float* W2  = (const float*)d_in[6];
    const float* b2  = (const float*)d_in[7];
    const float* Wl1 = (const float*)d_in[8];
    const float* bl1 = (const float*)d_in[9];
    const float* Wl2 = (const float*)d_in[10];
    const float* bl2 = (const float*)d_in[11];
    int N = in_sizes[0];
    int E = in_sizes[1];
    int G = out_size;
    float* out = (float*)d_out;

    char* ws = (char*)d_ws;
    size_t o = 0;
    auto alloc = [&](size_t bytes) -> void* {
        o = (o + 255) & ~(size_t)255;
        void* p = ws + o;
        o += bytes;
        return p;
    };
    int*    deg    = (int*)alloc((size_t)N * 4);
    int*    cursor = (int*)alloc((size_t)N * 4);
    int*    off    = (int*)alloc((size_t)(N + 1) * 4);
    int*    nbr    = (int*)alloc((size_t)E * 4);
    float*  dinv   = (float*)alloc((size_t)N * 4);
    float*  aggx   = (float*)alloc((size_t)N * 4);
    float*  aggh   = (float*)alloc((size_t)N * F1 * 4);
    double* pooled = (double*)alloc((size_t)G * F2 * 8);
    int*    counts = (int*)alloc((size_t)G * 4);
    int*    starts = (int*)alloc((size_t)(G + 1) * 4);

    hipMemsetAsync(deg, 0, (size_t)N * 4, stream);
    hipMemsetAsync(cursor, 0, (size_t)N * 4, stream);
    hipMemsetAsync(pooled, 0, (size_t)G * F2 * 8, stream);

    int tE = (E + 255) / 256;
    int tN = (N + 255) / 256;
    k_count_deg<<<tE, 256, 0, stream>>>(dst, E, deg);
    k_batch_bounds<<<1, 128, 0, stream>>>(batch, N, G, starts, counts);
    k_dinv_self<<<tN, 256, 0, stream>>>(deg, x, N, dinv, aggx);
    k_scan<<<1, SCAN_T, 0, stream>>>(deg, N, off);
    k_fill_agg<<<tE, 256, 0, stream>>>(src, dst, E, off, cursor, nbr, x, dinv, aggx);
    k_aggh<<<(N + 3) / 4, 256, 0, stream>>>(off, nbr, aggx, dinv, W1, b1, N, aggh);
    k_h2_pool<<<(N + NPB - 1) / NPB, 256, 0, stream>>>(aggh, W2, b2, batch, N, pooled);
    k_head<<<G, 256, 0, stream>>>(pooled, counts, Wl1, bl1, Wl2, bl2, out);
}

// Round 4
// 656.758 us; speedup vs baseline: 2.1871x; 1.0256x over previous
//
#include <hip/hip_runtime.h>
#include <math.h>

#define F1 100
#define F2 200

__device__ __forceinline__ float siluf(float v) {
    return v / (1.0f + expf(-v));
}

__global__ void k_count_deg(const int* __restrict__ dst, int E, int* __restrict__ deg) {
    int i = blockIdx.x * blockDim.x + threadIdx.x;
    if (i < E) atomicAdd(&deg[dst[i]], 1);
}

// batch is sorted: counts via binary-searched boundaries, no atomics.
__global__ void k_batch_bounds(const int* __restrict__ batch, int N, int G,
                               int* __restrict__ starts, int* __restrict__ counts) {
    int t = threadIdx.x;
    if (t <= G) {
        int lo = 0, hi = N;
        while (lo < hi) {
            int mid = (lo + hi) >> 1;
            if (batch[mid] < t) lo = mid + 1; else hi = mid;
        }
        starts[t] = lo;
    }
    __syncthreads();
    if (t < G) counts[t] = starts[t + 1] - starts[t];
}

__global__ void k_dinv_self(const int* __restrict__ deg, const float* __restrict__ x, int N,
                            float* __restrict__ dinv, float* __restrict__ aggx) {
    int i = blockIdx.x * blockDim.x + threadIdx.x;
    if (i < N) {
        float d = 1.0f / sqrtf((float)deg[i] + 1.0f);
        dinv[i] = d;
        aggx[i] = x[i] * d * d;   // self-loop message, layer 1 (scalar feature)
    }
}

#define SCAN_T 1024
__global__ void k_scan(const int* __restrict__ deg, int N, int* __restrict__ off) {
    __shared__ int part[SCAN_T];
    int t = threadIdx.x;
    int chunk = (N + SCAN_T - 1) / SCAN_T;
    int beg = t * chunk;
    int end = min(beg + chunk, N);
    int s = 0;
    for (int i = beg; i < end; ++i) s += deg[i];
    part[t] = s;
    __syncthreads();
    for (int ofs = 1; ofs < SCAN_T; ofs <<= 1) {
        int v = (t >= ofs) ? part[t - ofs] : 0;
        __syncthreads();
        part[t] += v;
        __syncthreads();
    }
    int run = (t == 0) ? 0 : part[t - 1];
    for (int i = beg; i < end; ++i) { off[i] = run; run += deg[i]; }
    if (t == SCAN_T - 1) off[N] = part[SCAN_T - 1];
}

// Fused CSR fill + scalar layer-1 edge aggregation (single pass over src/dst).
__global__ void k_fill_agg(const int* __restrict__ src, const int* __restrict__ dst, int E,
                           const int* __restrict__ off, int* __restrict__ cursor,
                           int* __restrict__ nbr,
                           const float* __restrict__ x, const float* __restrict__ dinv,
                           float* __restrict__ aggx) {
    int e = blockIdx.x * blockDim.x + threadIdx.x;
    if (e < E) {
        int s = src[e], d = dst[e];
        int p = atomicAdd(&cursor[d], 1);
        nbr[off[d] + p] = s;
        atomicAdd(&aggx[d], x[s] * dinv[s] * dinv[d]);
    }
}

// Materialize layer-1 output rows once per node: h1[n][j] = silu(aggx[n]*W1[j]+b1[j]).
// Thread computes a float2 (two features); 50 float2 per node.
__global__ void k_h1(const float* __restrict__ aggx, const float* __restrict__ W1,
                     const float* __restrict__ b1, int N, float* __restrict__ h1) {
    int idx = blockIdx.x * blockDim.x + threadIdx.x;
    int total = N * (F1 / 2);
    if (idx >= total) return;
    int n = idx / (F1 / 2);
    int p = idx % (F1 / 2);
    float a = aggx[n];
    float2 w = ((const float2*)W1)[p];
    float2 bb = ((const float2*)b1)[p];
    float2 r;
    r.x = siluf(fmaf(a, w.x, bb.x));
    r.y = siluf(fmaf(a, w.y, bb.y));
    ((float2*)h1)[idx] = r;
}

// Layer-2 aggregation as a pure gather of materialized h1 rows.
// One wave per node; lanes 0..49 hold the 100-float row as float2.
__global__ __launch_bounds__(256) void k_aggh_gather(
    const int* __restrict__ off, const int* __restrict__ nbr,
    const float* __restrict__ h1, const float* __restrict__ dinv,
    int N, float* __restrict__ aggh)
{
    int wave = threadIdx.x >> 6;
    int lane = threadIdx.x & 63;
    int n = blockIdx.x * 4 + wave;
    if (n >= N) return;
    const float2* h1f2 = (const float2*)h1;
    float d0 = dinv[n];
    bool act = lane < (F1 / 2);
    float accx = 0.0f, accy = 0.0f;
    if (act) {
        float2 v = h1f2[(size_t)n * (F1 / 2) + lane];
        accx = v.x * d0 * d0;   // self-loop term
        accy = v.y * d0 * d0;
    }
    int beg = off[n], end = off[n + 1];
    for (int t = beg; t < end; t += 64) {
        int cnt = min(64, end - t);
        int sn = 0; float sw = 0.0f;
        if (lane < cnt) {
            sn = nbr[t + lane];
            sw = dinv[sn] * d0;
        }
        int i = 0;
        for (; i + 1 < cnt; i += 2) {
            int   s0 = __shfl(sn, i),     s1 = __shfl(sn, i + 1);
            float w0 = __shfl(sw, i),     w1 = __shfl(sw, i + 1);
            if (act) {
                float2 v0 = h1f2[(size_t)s0 * (F1 / 2) + lane];
                float2 v1 = h1f2[(size_t)s1 * (F1 / 2) + lane];
                accx = fmaf(w0, v0.x, accx); accy = fmaf(w0, v0.y, accy);
                accx = fmaf(w1, v1.x, accx); accy = fmaf(w1, v1.y, accy);
            }
        }
        if (i < cnt) {
            int   s0 = __shfl(sn, i);
            float w0 = __shfl(sw, i);
            if (act) {
                float2 v0 = h1f2[(size_t)s0 * (F1 / 2) + lane];
                accx = fmaf(w0, v0.x, accx); accy = fmaf(w0, v0.y, accy);
            }
        }
    }
    if (act) {
        float2 r; r.x = accx; r.y = accy;
        ((float2*)aggh)[(size_t)n * (F1 / 2) + lane] = r;
    }
}

// Fallback (ws too small for h1): layer-2 aggregation with on-the-fly recompute.
__global__ __launch_bounds__(256) void k_aggh(
    const int* __restrict__ off, const int* __restrict__ nbr,
    const float* __restrict__ aggx, const float* __restrict__ dinv,
    const float* __restrict__ W1, const float* __restrict__ b1,
    int N, float* __restrict__ aggh)
{
    int wave = threadIdx.x >> 6;
    int lane = threadIdx.x & 63;
    int n = blockIdx.x * 4 + wave;
    if (n >= N) return;
    int ja = lane;
    int jb = lane + 64;
    float w1a = (ja < F1) ? W1[ja] : 0.0f;
    float b1a = (ja < F1) ? b1[ja] : 0.0f;
    float w1b = (jb < F1) ? W1[jb] : 0.0f;
    float b1b = (jb < F1) ? b1[jb] : 0.0f;
    float d0 = dinv[n];
    float a0 = aggx[n];
    float accA = siluf(fmaf(a0, w1a, b1a)) * (d0 * d0);
    float accB = siluf(fmaf(a0, w1b, b1b)) * (d0 * d0);
    int beg = off[n], end = off[n + 1];
    for (int t = beg; t < end; t += 64) {
        int cnt = min(64, end - t);
        float sa = 0.0f, sw = 0.0f;
        if (lane < cnt) {
            int s = nbr[t + lane];
            sa = aggx[s];
            sw = dinv[s] * d0;
        }
        for (int i = 0; i < cnt; ++i) {
            float ai = __shfl(sa, i);
            float wi = __shfl(sw, i);
            accA += wi * siluf(fmaf(ai, w1a, b1a));
            accB += wi * siluf(fmaf(ai, w1b, b1b));
        }
    }
    if (ja < F1) aggh[(size_t)n * F1 + ja] = accA;
    if (jb < F1) aggh[(size_t)n * F1 + jb] = accB;
}

// Fused: h2 = silu(aggh @ W2 + b2), pooled[batch[n]] += h2 (double accumulation).
#define NPB 64
#define STAGE 8
__global__ __launch_bounds__(256) void k_h2_pool(
    const float* __restrict__ aggh, const float* __restrict__ W2, const float* __restrict__ b2,
    const int* __restrict__ batch, int N, double* __restrict__ pooled)
{
    __shared__ float sh[STAGE][F1];
    __shared__ int sbatch[NPB];
    int tid = threadIdx.x;
    int base = blockIdx.x * NPB;
    int m = tid;
    float w2c[F1];
    if (m < F2) {
        #pragma unroll
        for (int j = 0; j < F1; ++j) w2c[j] = W2[j * F2 + m];
    }
    float bb = (m < F2) ? b2[m] : 0.0f;
    if (tid < NPB && base + tid < N) sbatch[tid] = batch[base + tid];
    __syncthreads();
    double pl = 0.0;
    int gcur = -1;
    for (int t0 = 0; t0 < NPB; t0 += STAGE) {
        for (int idx = tid; idx < STAGE * F1; idx += 256) {
            int r = idx / F1, c = idx % F1;
            int n = base + t0 + r;
            sh[r][c] = (n < N) ? aggh[(size_t)n * F1 + c] : 0.0f;
        }
        __syncthreads();
        for (int r = 0; r < STAGE; ++r) {
            int n = base + t0 + r;
            if (n >= N) break;
            int g = sbatch[t0 + r];
            if (g != gcur) {
                if (gcur >= 0 && m < F2) atomicAdd(&pooled[(size_t)gcur * F2 + m], pl);
                pl = 0.0;
                gcur = g;
            }
            if (m < F2) {
                float acc = bb;
                #pragma unroll
                for (int j = 0; j < F1; ++j) acc = fmaf(sh[r][j], w2c[j], acc);
                pl += (double)siluf(acc);
            }
        }
        __syncthreads();
    }
    if (gcur >= 0 && m < F2) atomicAdd(&pooled[(size_t)gcur * F2 + m], pl);
}

// Head MLP: one block per graph, double precision.
__global__ __launch_bounds__(256) void k_head(
    const double* __restrict__ pooled, const int* __restrict__ counts,
    const float* __restrict__ Wl1, const float* __restrict__ bl1,
    const float* __restrict__ Wl2, const float* __restrict__ bl2,
    float* __restrict__ out)
{
    int g = blockIdx.x;
    int tid = threadIdx.x;
    __shared__ double sp[F2];
    __shared__ double red[256];
    double icnt = 1.0 / (double)max(counts[g], 1);
    for (int m = tid; m < F2; m += 256) sp[m] = pooled[(size_t)g * F2 + m] * icnt;
    __syncthreads();
    double part = 0.0;
    if (tid < 100) {
        double acc = (double)bl1[tid];
        #pragma unroll 4
        for (int m = 0; m < F2; ++m) acc += sp[m] * (double)Wl1[m * 100 + tid];
        double t1 = acc / (1.0 + exp(-acc));
        part = t1 * (double)Wl2[tid];
    }
    red[tid] = part;
    __syncthreads();
    for (int s = 128; s > 0; s >>= 1) {
        if (tid < s) red[tid] += red[tid + s];
        __syncthreads();
    }
    if (tid == 0) out[g] = (float)(red[0] + (double)bl2[0]);
}

extern "C" void kernel_launch(void* const* d_in, const int* in_sizes, int n_in,
                              void* d_out, int out_size, void* d_ws, size_t ws_size,
                              hipStream_t stream)
{
    const float* x   = (const float*)d_in[0];
    const int*   src = (const int*)d_in[1];
    const int*   dst = (const int*)d_in[2];
    const int*   batch = (const int*)d_in[3];
    const float* W1  = (const float*)d_in[4];
    const float* b1  = (const float*)d_in[5];
    const float* W2  = (const float*)d_in[6];
    const float* b2  = (const float*)d_in[7];
    const float* Wl1 = (const float*)d_in[8];
    const float* bl1 = (const float*)d_in[9];
    const float* Wl2 = (const float*)d_in[10];
    const float* bl2 = (const float*)d_in[11];
    int N = in_sizes[0];
    int E = in_sizes[1];
    int G = out_size;
    float* out = (float*)d_out;

    char* ws = (char*)d_ws;
    size_t o = 0;
    auto alloc = [&](size_t bytes) -> void* {
        o = (o + 255) & ~(size_t)255;
        void* p = ws + o;
        o += bytes;
        return p;
    };
    int*    deg    = (int*)alloc((size_t)N * 4);
    int*    cursor = (int*)alloc((size_t)N * 4);
    int*    off    = (int*)alloc((size_t)(N + 1) * 4);
    int*    nbr    = (int*)alloc((size_t)E * 4);
    float*  dinv   = (float*)alloc((size_t)N * 4);
    float*  aggx   = (float*)alloc((size_t)N * 4);
    float*  aggh   = (float*)alloc((size_t)N * F1 * 4);
    double* pooled = (double*)alloc((size_t)G * F2 * 8);
    int*    counts = (int*)alloc((size_t)G * 4);
    int*    starts = (int*)alloc((size_t)(G + 1) * 4);
    // h1 last: gate on remaining workspace, fallback to recompute path if absent.
    o = (o + 255) & ~(size_t)255;
    float* h1 = (float*)(ws + o);
    bool use_h1 = (o + (size_t)N * F1 * 4) <= ws_size;

    hipMemsetAsync(deg, 0, (size_t)N * 4, stream);
    hipMemsetAsync(cursor, 0, (size_t)N * 4, stream);
    hipMemsetAsync(pooled, 0, (size_t)G * F2 * 8, stream);

    int tE = (E + 255) / 256;
    int tN = (N + 255) / 256;
    k_count_deg<<<tE, 256, 0, stream>>>(dst, E, deg);
    k_batch_bounds<<<1, 128, 0, stream>>>(batch, N, G, starts, counts);
    k_dinv_self<<<tN, 256, 0, stream>>>(deg, x, N, dinv, aggx);
    k_scan<<<1, SCAN_T, 0, stream>>>(deg, N, off);
    k_fill_agg<<<tE, 256, 0, stream>>>(src, dst, E, off, cursor, nbr, x, dinv, aggx);
    if (use_h1) {
        int th1 = (N * (F1 / 2) + 255) / 256;
        k_h1<<<th1, 256, 0, stream>>>(aggx, W1, b1, N, h1);
        k_aggh_gather<<<(N + 3) / 4, 256, 0, stream>>>(off, nbr, h1, dinv, N, aggh);
    } else {
        k_aggh<<<(N + 3) / 4, 256, 0, stream>>>(off, nbr, aggx, dinv, W1, b1, N, aggh);
    }
    k_h2_pool<<<(N + NPB - 1) / NPB, 256, 0, stream>>>(aggh, W2, b2, batch, N, pooled);
    k_head<<<G, 256, 0, stream>>>(pooled, counts, Wl1, bl1, Wl2, bl2, out);
}

// Round 5
// 508.591 us; speedup vs baseline: 2.8243x; 1.2913x over previous
//
#include <hip/hip_runtime.h>
#include <math.h>

#define F1 100
#define F2 200

__device__ __forceinline__ float siluf(float v) {
    return v / (1.0f + expf(-v));
}

__global__ void k_count_deg(const int* __restrict__ dst, int E, int* __restrict__ deg) {
    int i = blockIdx.x * blockDim.x + threadIdx.x;
    if (i < E) atomicAdd(&deg[dst[i]], 1);
}

// batch is sorted: counts via binary-searched boundaries, no atomics.
__global__ void k_batch_bounds(const int* __restrict__ batch, int N, int G,
                               int* __restrict__ starts, int* __restrict__ counts) {
    int t = threadIdx.x;
    if (t <= G) {
        int lo = 0, hi = N;
        while (lo < hi) {
            int mid = (lo + hi) >> 1;
            if (batch[mid] < t) lo = mid + 1; else hi = mid;
        }
        starts[t] = lo;
    }
    __syncthreads();
    if (t < G) counts[t] = starts[t + 1] - starts[t];
}

__global__ void k_dinv_self(const int* __restrict__ deg, const float* __restrict__ x, int N,
                            float* __restrict__ dinv, float* __restrict__ aggx) {
    int i = blockIdx.x * blockDim.x + threadIdx.x;
    if (i < N) {
        float d = 1.0f / sqrtf((float)deg[i] + 1.0f);
        dinv[i] = d;
        aggx[i] = x[i] * d * d;   // self-loop message, layer 1 (scalar feature)
    }
}

// ---- multi-block exclusive scan of deg -> off (3 phases) ----
#define SCHUNK 2048   // elements per block (256 threads x 8)

__global__ __launch_bounds__(256) void k_scan_partial(const int* __restrict__ deg, int N,
                                                      int* __restrict__ partials) {
    __shared__ int red[256];
    int base = blockIdx.x * SCHUNK;
    int s = 0;
    for (int i = threadIdx.x; i < SCHUNK; i += 256) {
        int idx = base + i;
        if (idx < N) s += deg[idx];
    }
    red[threadIdx.x] = s;
    __syncthreads();
    for (int ofs = 128; ofs > 0; ofs >>= 1) {
        if (threadIdx.x < ofs) red[threadIdx.x] += red[threadIdx.x + ofs];
        __syncthreads();
    }
    if (threadIdx.x == 0) partials[blockIdx.x] = red[0];
}

__global__ __launch_bounds__(1024) void k_scan_blocks(int* __restrict__ partials, int nb) {
    __shared__ int sh[1024];
    int t = threadIdx.x;
    int v = (t < nb) ? partials[t] : 0;
    sh[t] = v;
    __syncthreads();
    for (int ofs = 1; ofs < 1024; ofs <<= 1) {
        int u = (t >= ofs) ? sh[t - ofs] : 0;
        __syncthreads();
        sh[t] += u;
        __syncthreads();
    }
    if (t < nb) partials[t] = sh[t] - v;   // exclusive
}

__global__ __launch_bounds__(256) void k_scan_final(const int* __restrict__ deg, int N,
                                                    const int* __restrict__ partials,
                                                    int* __restrict__ off) {
    __shared__ int sh[256];
    int base = blockIdx.x * SCHUNK;
    int i0 = base + threadIdx.x * 8;
    int v[8];
    int s = 0;
    #pragma unroll
    for (int j = 0; j < 8; ++j) {
        int idx = i0 + j;
        v[j] = (idx < N) ? deg[idx] : 0;
        s += v[j];
    }
    int mine = s;
    sh[threadIdx.x] = s;
    __syncthreads();
    for (int ofs = 1; ofs < 256; ofs <<= 1) {
        int u = (threadIdx.x >= ofs) ? sh[threadIdx.x - ofs] : 0;
        __syncthreads();
        sh[threadIdx.x] += u;
        __syncthreads();
    }
    int run = partials[blockIdx.x] + sh[threadIdx.x] - mine;
    #pragma unroll
    for (int j = 0; j < 8; ++j) {
        int idx = i0 + j;
        if (idx < N) { off[idx] = run; run += v[j]; }
    }
    if (N >= i0 && N <= i0 + 8) off[N] = run;   // exclusive total at position N
}

// Fused CSR fill + scalar layer-1 edge aggregation (single pass over src/dst).
__global__ void k_fill_agg(const int* __restrict__ src, const int* __restrict__ dst, int E,
                           const int* __restrict__ off, int* __restrict__ cursor,
                           int* __restrict__ nbr,
                           const float* __restrict__ x, const float* __restrict__ dinv,
                           float* __restrict__ aggx) {
    int e = blockIdx.x * blockDim.x + threadIdx.x;
    if (e < E) {
        int s = src[e], d = dst[e];
        int p = atomicAdd(&cursor[d], 1);
        nbr[off[d] + p] = s;
        atomicAdd(&aggx[d], x[s] * dinv[s] * dinv[d]);
    }
}

// Materialize layer-1 output rows once per node: h1[n][j] = silu(aggx[n]*W1[j]+b1[j]).
__global__ void k_h1(const float* __restrict__ aggx, const float* __restrict__ W1,
                     const float* __restrict__ b1, int N, float* __restrict__ h1) {
    int idx = blockIdx.x * blockDim.x + threadIdx.x;
    int total = N * (F1 / 2);
    if (idx >= total) return;
    int n = idx / (F1 / 2);
    int p = idx % (F1 / 2);
    float a = aggx[n];
    float2 w = ((const float2*)W1)[p];
    float2 bb = ((const float2*)b1)[p];
    float2 r;
    r.x = siluf(fmaf(a, w.x, bb.x));
    r.y = siluf(fmaf(a, w.y, bb.y));
    ((float2*)h1)[idx] = r;
}

// Layer-2 aggregation as a pure gather of materialized h1 rows.
// One wave per node; lanes 0..49 hold the 100-float row as float2.
__global__ __launch_bounds__(256) void k_aggh_gather(
    const int* __restrict__ off, const int* __restrict__ nbr,
    const float* __restrict__ h1, const float* __restrict__ dinv,
    int N, float* __restrict__ aggh)
{
    int wave = threadIdx.x >> 6;
    int lane = threadIdx.x & 63;
    int n = blockIdx.x * 4 + wave;
    if (n >= N) return;
    const float2* h1f2 = (const float2*)h1;
    float d0 = dinv[n];
    bool act = lane < (F1 / 2);
    float accx = 0.0f, accy = 0.0f;
    if (act) {
        float2 v = h1f2[(size_t)n * (F1 / 2) + lane];
        accx = v.x * d0 * d0;   // self-loop term
        accy = v.y * d0 * d0;
    }
    int beg = off[n], end = off[n + 1];
    for (int t = beg; t < end; t += 64) {
        int cnt = min(64, end - t);
        int sn = 0; float sw = 0.0f;
        if (lane < cnt) {
            sn = nbr[t + lane];
            sw = dinv[sn] * d0;
        }
        int i = 0;
        for (; i + 1 < cnt; i += 2) {
            int   s0 = __shfl(sn, i),     s1 = __shfl(sn, i + 1);
            float w0 = __shfl(sw, i),     w1 = __shfl(sw, i + 1);
            if (act) {
                float2 v0 = h1f2[(size_t)s0 * (F1 / 2) + lane];
                float2 v1 = h1f2[(size_t)s1 * (F1 / 2) + lane];
                accx = fmaf(w0, v0.x, accx); accy = fmaf(w0, v0.y, accy);
                accx = fmaf(w1, v1.x, accx); accy = fmaf(w1, v1.y, accy);
            }
        }
        if (i < cnt) {
            int   s0 = __shfl(sn, i);
            float w0 = __shfl(sw, i);
            if (act) {
                float2 v0 = h1f2[(size_t)s0 * (F1 / 2) + lane];
                accx = fmaf(w0, v0.x, accx); accy = fmaf(w0, v0.y, accy);
            }
        }
    }
    if (act) {
        float2 r; r.x = accx; r.y = accy;
        ((float2*)aggh)[(size_t)n * (F1 / 2) + lane] = r;
    }
}

// Fallback (ws too small for h1): layer-2 aggregation with on-the-fly recompute.
__global__ __launch_bounds__(256) void k_aggh(
    const int* __restrict__ off, const int* __restrict__ nbr,
    const float* __restrict__ aggx, const float* __restrict__ dinv,
    const float* __restrict__ W1, const float* __restrict__ b1,
    int N, float* __restrict__ aggh)
{
    int wave = threadIdx.x >> 6;
    int lane = threadIdx.x & 63;
    int n = blockIdx.x * 4 + wave;
    if (n >= N) return;
    int ja = lane;
    int jb = lane + 64;
    float w1a = (ja < F1) ? W1[ja] : 0.0f;
    float b1a = (ja < F1) ? b1[ja] : 0.0f;
    float w1b = (jb < F1) ? W1[jb] : 0.0f;
    float b1b = (jb < F1) ? b1[jb] : 0.0f;
    float d0 = dinv[n];
    float a0 = aggx[n];
    float accA = siluf(fmaf(a0, w1a, b1a)) * (d0 * d0);
    float accB = siluf(fmaf(a0, w1b, b1b)) * (d0 * d0);
    int beg = off[n], end = off[n + 1];
    for (int t = beg; t < end; t += 64) {
        int cnt = min(64, end - t);
        float sa = 0.0f, sw = 0.0f;
        if (lane < cnt) {
            int s = nbr[t + lane];
            sa = aggx[s];
            sw = dinv[s] * d0;
        }
        for (int i = 0; i < cnt; ++i) {
            float ai = __shfl(sa, i);
            float wi = __shfl(sw, i);
            accA += wi * siluf(fmaf(ai, w1a, b1a));
            accB += wi * siluf(fmaf(ai, w1b, b1b));
        }
    }
    if (ja < F1) aggh[(size_t)n * F1 + ja] = accA;
    if (jb < F1) aggh[(size_t)n * F1 + jb] = accB;
}

// Fused: h2 = silu(aggh @ W2 + b2), pooled[batch[n]] += h2 (double accumulation).
#define NPB 64
#define STAGE 8
__global__ __launch_bounds__(256) void k_h2_pool(
    const float* __restrict__ aggh, const float* __restrict__ W2, const float* __restrict__ b2,
    const int* __restrict__ batch, int N, double* __restrict__ pooled)
{
    __shared__ float sh[STAGE][F1];
    __shared__ int sbatch[NPB];
    int tid = threadIdx.x;
    int base = blockIdx.x * NPB;
    int m = tid;
    float w2c[F1];
    if (m < F2) {
        #pragma unroll
        for (int j = 0; j < F1; ++j) w2c[j] = W2[j * F2 + m];
    }
    float bb = (m < F2) ? b2[m] : 0.0f;
    if (tid < NPB && base + tid < N) sbatch[tid] = batch[base + tid];
    __syncthreads();
    double pl = 0.0;
    int gcur = -1;
    for (int t0 = 0; t0 < NPB; t0 += STAGE) {
        for (int idx = tid; idx < STAGE * F1; idx += 256) {
            int r = idx / F1, c = idx % F1;
            int n = base + t0 + r;
            sh[r][c] = (n < N) ? aggh[(size_t)n * F1 + c] : 0.0f;
        }
        __syncthreads();
        for (int r = 0; r < STAGE; ++r) {
            int n = base + t0 + r;
            if (n >= N) break;
            int g = sbatch[t0 + r];
            if (g != gcur) {
                if (gcur >= 0 && m < F2) atomicAdd(&pooled[(size_t)gcur * F2 + m], pl);
                pl = 0.0;
                gcur = g;
            }
            if (m < F2) {
                float acc = bb;
                #pragma unroll
                for (int j = 0; j < F1; ++j) acc = fmaf(sh[r][j], w2c[j], acc);
                pl += (double)siluf(acc);
            }
        }
        __syncthreads();
    }
    if (gcur >= 0 && m < F2) atomicAdd(&pooled[(size_t)gcur * F2 + m], pl);
}

// Head MLP: one block per graph, double precision.
__global__ __launch_bounds__(256) void k_head(
    const double* __restrict__ pooled, const int* __restrict__ counts,
    const float* __restrict__ Wl1, const float* __restrict__ bl1,
    const float* __restrict__ Wl2, const float* __restrict__ bl2,
    float* __restrict__ out)
{
    int g = blockIdx.x;
    int tid = threadIdx.x;
    __shared__ double sp[F2];
    __shared__ double red[256];
    double icnt = 1.0 / (double)max(counts[g], 1);
    for (int m = tid; m < F2; m += 256) sp[m] = pooled[(size_t)g * F2 + m] * icnt;
    __syncthreads();
    double part = 0.0;
    if (tid < 100) {
        double acc = (double)bl1[tid];
        #pragma unroll 4
        for (int m = 0; m < F2; ++m) acc += sp[m] * (double)Wl1[m * 100 + tid];
        double t1 = acc / (1.0 + exp(-acc));
        part = t1 * (double)Wl2[tid];
    }
    red[tid] = part;
    __syncthreads();
    for (int s = 128; s > 0; s >>= 1) {
        if (tid < s) red[tid] += red[tid + s];
        __syncthreads();
    }
    if (tid == 0) out[g] = (float)(red[0] + (double)bl2[0]);
}

extern "C" void kernel_launch(void* const* d_in, const int* in_sizes, int n_in,
                              void* d_out, int out_size, void* d_ws, size_t ws_size,
                              hipStream_t stream)
{
    const float* x   = (const float*)d_in[0];
    const int*   src = (const int*)d_in[1];
    const int*   dst = (const int*)d_in[2];
    const int*   batch = (const int*)d_in[3];
    const float* W1  = (const float*)d_in[4];
    const float* b1  = (const float*)d_in[5];
    const float* W2  = (const float*)d_in[6];
    const float* b2  = (const float*)d_in[7];
    const float* Wl1 = (const float*)d_in[8];
    const float* bl1 = (const float*)d_in[9];
    const float* Wl2 = (const float*)d_in[10];
    const float* bl2 = (const float*)d_in[11];
    int N = in_sizes[0];
    int E = in_sizes[1];
    int G = out_size;
    float* out = (float*)d_out;

    char* ws = (char*)d_ws;
    size_t o = 0;
    auto alloc = [&](size_t bytes) -> void* {
        o = (o + 255) & ~(size_t)255;
        void* p = ws + o;
        o += bytes;
        return p;
    };
    int nscan = (N + SCHUNK - 1) / SCHUNK;
    int*    deg    = (int*)alloc((size_t)N * 4);
    int*    cursor = (int*)alloc((size_t)N * 4);
    int*    off    = (int*)alloc((size_t)(N + 1) * 4);
    int*    nbr    = (int*)alloc((size_t)E * 4);
    float*  dinv   = (float*)alloc((size_t)N * 4);
    float*  aggx   = (float*)alloc((size_t)N * 4);
    float*  aggh   = (float*)alloc((size_t)N * F1 * 4);
    double* pooled = (double*)alloc((size_t)G * F2 * 8);
    int*    counts = (int*)alloc((size_t)G * 4);
    int*    starts = (int*)alloc((size_t)(G + 1) * 4);
    int*    partials = (int*)alloc((size_t)nscan * 4);
    // h1 last: gate on remaining workspace, fallback to recompute path if absent.
    o = (o + 255) & ~(size_t)255;
    float* h1 = (float*)(ws + o);
    bool use_h1 = (o + (size_t)N * F1 * 4) <= ws_size;

    hipMemsetAsync(deg, 0, (size_t)N * 4, stream);
    hipMemsetAsync(cursor, 0, (size_t)N * 4, stream);
    hipMemsetAsync(pooled, 0, (size_t)G * F2 * 8, stream);

    int tE = (E + 255) / 256;
    int tN = (N + 255) / 256;
    k_count_deg<<<tE, 256, 0, stream>>>(dst, E, deg);
    k_batch_bounds<<<1, 128, 0, stream>>>(batch, N, G, starts, counts);
    k_dinv_self<<<tN, 256, 0, stream>>>(deg, x, N, dinv, aggx);
    k_scan_partial<<<nscan, 256, 0, stream>>>(deg, N, partials);
    k_scan_blocks<<<1, 1024, 0, stream>>>(partials, nscan);
    k_scan_final<<<nscan, 256, 0, stream>>>(deg, N, partials, off);
    k_fill_agg<<<tE, 256, 0, stream>>>(src, dst, E, off, cursor, nbr, x, dinv, aggx);
    if (use_h1) {
        int th1 = (N * (F1 / 2) + 255) / 256;
        k_h1<<<th1, 256, 0, stream>>>(aggx, W1, b1, N, h1);
        k_aggh_gather<<<(N + 3) / 4, 256, 0, stream>>>(off, nbr, h1, dinv, N, aggh);
    } else {
        k_aggh<<<(N + 3) / 4, 256, 0, stream>>>(off, nbr, aggx, dinv, W1, b1, N, aggh);
    }
    k_h2_pool<<<(N + NPB - 1) / NPB, 256, 0, stream>>>(aggh, W2, b2, batch, N, pooled);
    k_head<<<G, 256, 0, stream>>>(pooled, counts, Wl1, bl1, Wl2, bl2, out);
}

// Round 6
// 371.534 us; speedup vs baseline: 3.8662x; 1.3689x over previous
//
#include <hip/hip_runtime.h>
#include <math.h>

#define F1 100
#define F2 200

// bucket width 512 nodes
#define BW_LOG 9
#define BW 512

__device__ __forceinline__ float siluf(float v) {
    return v / (1.0f + expf(-v));
}

// batch is sorted: counts via binary-searched boundaries, no atomics.
__global__ void k_batch_bounds(const int* __restrict__ batch, int N, int G,
                               int* __restrict__ starts, int* __restrict__ counts) {
    int t = threadIdx.x;
    if (t <= G) {
        int lo = 0, hi = N;
        while (lo < hi) {
            int mid = (lo + hi) >> 1;
            if (batch[mid] < t) lo = mid + 1; else hi = mid;
        }
        starts[t] = lo;
    }
    __syncthreads();
    if (t < G) counts[t] = starts[t + 1] - starts[t];
}

// ---- bucketed CSR build ----

// A: per-bucket edge histogram (LDS staged, one flush per block).
__global__ __launch_bounds__(256) void k_bucket_count(const int* __restrict__ dst, int E,
                                                      int nbk, int* __restrict__ gcnt) {
    extern __shared__ int cnt[];
    for (int i = threadIdx.x; i < nbk; i += 256) cnt[i] = 0;
    __syncthreads();
    for (int e = blockIdx.x * 256 + threadIdx.x; e < E; e += gridDim.x * 256)
        atomicAdd(&cnt[dst[e] >> BW_LOG], 1);
    __syncthreads();
    for (int i = threadIdx.x; i < nbk; i += 256)
        if (cnt[i]) atomicAdd(&gcnt[i], cnt[i]);
}

// B: exclusive scan of bucket counts -> base; init cursor.
__global__ __launch_bounds__(256) void k_bucket_scan(const int* __restrict__ gcnt, int nbk, int E,
                                                     int* __restrict__ base, int* __restrict__ cursor) {
    __shared__ int sh[256];
    int t = threadIdx.x;
    int v = (t < nbk) ? gcnt[t] : 0;
    sh[t] = v;
    __syncthreads();
    for (int ofs = 1; ofs < 256; ofs <<= 1) {
        int u = (t >= ofs) ? sh[t - ofs] : 0;
        __syncthreads();
        sh[t] += u;
        __syncthreads();
    }
    if (t < nbk) { int ex = sh[t] - v; base[t] = ex; cursor[t] = ex; }
    if (t == 0) base[nbk] = E;
}

// C: scatter (src,dst) pairs into bucket regions with LDS staging (2048 edges/round).
#define CROUND 2048
__global__ __launch_bounds__(256) void k_bucket_scatter(
    const int* __restrict__ src, const int* __restrict__ dst, int E, int nbk,
    int* __restrict__ gcursor, const int* __restrict__ gbase_unused,
    unsigned long long* __restrict__ pairs) {
    __shared__ int cnt[256];
    __shared__ int scanb[256];
    __shared__ int startx[256];
    __shared__ int cur[256];
    __shared__ int gbase[256];
    __shared__ unsigned long long stage[CROUND];
    int tid = threadIdx.x;
    for (long long r0 = (long long)blockIdx.x * CROUND; r0 < E; r0 += (long long)gridDim.x * CROUND) {
        // (a) zero counts
        cnt[tid] = 0;
        __syncthreads();
        // (b) load 8 edges/thread, histogram
        int ss[8], dd[8], bb[8];
        bool va[8];
        #pragma unroll
        for (int j = 0; j < 8; ++j) {
            long long e = r0 + j * 256 + tid;
            va[j] = (e < E);
            if (va[j]) {
                ss[j] = src[e]; dd[j] = dst[e]; bb[j] = dd[j] >> BW_LOG;
                atomicAdd(&cnt[bb[j]], 1);
            }
        }
        __syncthreads();
        // (c) inclusive scan of cnt -> scanb; exclusive start; reserve global space
        scanb[tid] = cnt[tid];
        __syncthreads();
        for (int ofs = 1; ofs < 256; ofs <<= 1) {
            int u = (tid >= ofs) ? scanb[tid - ofs] : 0;
            __syncthreads();
            scanb[tid] += u;
            __syncthreads();
        }
        int ex = scanb[tid] - cnt[tid];
        startx[tid] = ex;
        cur[tid] = ex;
        if (tid < nbk && cnt[tid] > 0) gbase[tid] = atomicAdd(&gcursor[tid], cnt[tid]);
        __syncthreads();
        int total = scanb[255];
        // (d) stage edges bucket-sorted in LDS
        #pragma unroll
        for (int j = 0; j < 8; ++j) {
            if (va[j]) {
                int slot = atomicAdd(&cur[bb[j]], 1);
                stage[slot] = ((unsigned long long)(unsigned)dd[j] << 32) | (unsigned)ss[j];
            }
        }
        __syncthreads();
        // (e) copy staged runs to global (bucket-sequential)
        for (int i = tid; i < total; i += 256) {
            unsigned long long p = stage[i];
            int b = (int)(p >> 32) >> BW_LOG;
            pairs[gbase[b] + (i - startx[b])] = p;
        }
        __syncthreads();
    }
}

// D1: per-bucket degree count (LDS) -> deg, dinv.
__global__ __launch_bounds__(512) void k_bucket_deg(
    const unsigned long long* __restrict__ pairs, const int* __restrict__ base,
    int N, int* __restrict__ deg, float* __restrict__ dinv) {
    __shared__ int dl[BW];
    int b = blockIdx.x;
    int t = threadIdx.x;
    dl[t] = 0;
    __syncthreads();
    int beg = base[b], end = base[b + 1];
    for (int i = beg + t; i < end; i += 512) {
        int d = (int)(pairs[i] >> 32);
        atomicAdd(&dl[d & (BW - 1)], 1);
    }
    __syncthreads();
    int node = (b << BW_LOG) + t;
    if (node < N) {
        int dg = dl[t];
        deg[node] = dg;
        dinv[node] = 1.0f / sqrtf((float)dg + 1.0f);
    }
}

// D2: per-bucket CSR fill (LDS cursors, L2-local nbr window) + layer-1 agg in LDS
// + h1 materialization for the bucket's nodes.
__global__ __launch_bounds__(512) void k_bucket_fill_h1(
    const unsigned long long* __restrict__ pairs, const int* __restrict__ base,
    const int* __restrict__ off, const float* __restrict__ x, const float* __restrict__ dinv,
    const float* __restrict__ W1, const float* __restrict__ b1,
    int N, int* __restrict__ nbr, float* __restrict__ h1) {
    __shared__ int offl[BW];
    __shared__ int cur[BW];
    __shared__ float agg[BW];
    int b = blockIdx.x;
    int t = threadIdx.x;
    int node0 = b << BW_LOG;
    int node = node0 + t;
    offl[t] = (node < N) ? off[node] : 0;
    cur[t] = 0;
    agg[t] = 0.0f;
    __syncthreads();
    int beg = base[b], end = base[b + 1];
    for (int i = beg + t; i < end; i += 512) {
        unsigned long long p = pairs[i];
        int s = (int)(p & 0xffffffffu);
        int d = (int)(p >> 32);
        int l = d & (BW - 1);
        int pos = atomicAdd(&cur[l], 1);
        nbr[offl[l] + pos] = s;
        atomicAdd(&agg[l], x[s] * dinv[s]);
    }
    __syncthreads();
    // h1 rows for this bucket: h1[n][j] = silu(aggx_n*W1[j]+b1[j]),
    // aggx_n = dinv_n*(agg_n + x_n*dinv_n)
    const float2* W1f2 = (const float2*)W1;
    const float2* b1f2 = (const float2*)b1;
    float2* h1f2 = (float2*)h1;
    int lim = BW * (F1 / 2);
    for (int idx = t; idx < lim; idx += 512) {
        int nl = idx / (F1 / 2);
        int pp = idx % (F1 / 2);
        int n = node0 + nl;
        if (n >= N) break;
        float dn = dinv[n];
        float a = dn * (agg[nl] + x[n] * dn);
        float2 w = W1f2[pp];
        float2 bb = b1f2[pp];
        float2 r;
        r.x = siluf(fmaf(a, w.x, bb.x));
        r.y = siluf(fmaf(a, w.y, bb.y));
        h1f2[(size_t)n * (F1 / 2) + pp] = r;
    }
}

// ---- multi-block exclusive scan of deg -> off (3 phases) ----
#define SCHUNK 2048

__global__ __launch_bounds__(256) void k_scan_partial(const int* __restrict__ deg, int N,
                                                      int* __restrict__ partials) {
    __shared__ int red[256];
    int base = blockIdx.x * SCHUNK;
    int s = 0;
    for (int i = threadIdx.x; i < SCHUNK; i += 256) {
        int idx = base + i;
        if (idx < N) s += deg[idx];
    }
    red[threadIdx.x] = s;
    __syncthreads();
    for (int ofs = 128; ofs > 0; ofs >>= 1) {
        if (threadIdx.x < ofs) red[threadIdx.x] += red[threadIdx.x + ofs];
        __syncthreads();
    }
    if (threadIdx.x == 0) partials[blockIdx.x] = red[0];
}

__global__ __launch_bounds__(1024) void k_scan_blocks(int* __restrict__ partials, int nb) {
    __shared__ int sh[1024];
    int t = threadIdx.x;
    int v = (t < nb) ? partials[t] : 0;
    sh[t] = v;
    __syncthreads();
    for (int ofs = 1; ofs < 1024; ofs <<= 1) {
        int u = (t >= ofs) ? sh[t - ofs] : 0;
        __syncthreads();
        sh[t] += u;
        __syncthreads();
    }
    if (t < nb) partials[t] = sh[t] - v;
}

__global__ __launch_bounds__(256) void k_scan_final(const int* __restrict__ deg, int N,
                                                    const int* __restrict__ partials,
                                                    int* __restrict__ off) {
    __shared__ int sh[256];
    int base = blockIdx.x * SCHUNK;
    int i0 = base + threadIdx.x * 8;
    int v[8];
    int s = 0;
    #pragma unroll
    for (int j = 0; j < 8; ++j) {
        int idx = i0 + j;
        v[j] = (idx < N) ? deg[idx] : 0;
        s += v[j];
    }
    int mine = s;
    sh[threadIdx.x] = s;
    __syncthreads();
    for (int ofs = 1; ofs < 256; ofs <<= 1) {
        int u = (threadIdx.x >= ofs) ? sh[threadIdx.x - ofs] : 0;
        __syncthreads();
        sh[threadIdx.x] += u;
        __syncthreads();
    }
    int run = partials[blockIdx.x] + sh[threadIdx.x] - mine;
    #pragma unroll
    for (int j = 0; j < 8; ++j) {
        int idx = i0 + j;
        if (idx < N) { off[idx] = run; run += v[j]; }
    }
    if (N >= i0 && N <= i0 + 8) off[N] = run;
}

// ---- fallback path kernels (ws too small for pairs/h1) ----
__global__ void k_count_deg(const int* __restrict__ dst, int E, int* __restrict__ deg) {
    int i = blockIdx.x * blockDim.x + threadIdx.x;
    if (i < E) atomicAdd(&deg[dst[i]], 1);
}

__global__ void k_dinv_self(const int* __restrict__ deg, const float* __restrict__ x, int N,
                            float* __restrict__ dinv, float* __restrict__ aggx) {
    int i = blockIdx.x * blockDim.x + threadIdx.x;
    if (i < N) {
        float d = 1.0f / sqrtf((float)deg[i] + 1.0f);
        dinv[i] = d;
        aggx[i] = x[i] * d * d;
    }
}

__global__ void k_fill_agg(const int* __restrict__ src, const int* __restrict__ dst, int E,
                           const int* __restrict__ off, int* __restrict__ cursor,
                           int* __restrict__ nbr,
                           const float* __restrict__ x, const float* __restrict__ dinv,
                           float* __restrict__ aggx) {
    int e = blockIdx.x * blockDim.x + threadIdx.x;
    if (e < E) {
        int s = src[e], d = dst[e];
        int p = atomicAdd(&cursor[d], 1);
        nbr[off[d] + p] = s;
        atomicAdd(&aggx[d], x[s] * dinv[s] * dinv[d]);
    }
}

__global__ __launch_bounds__(256) void k_aggh(
    const int* __restrict__ off, const int* __restrict__ nbr,
    const float* __restrict__ aggx, const float* __restrict__ dinv,
    const float* __restrict__ W1, const float* __restrict__ b1,
    int N, float* __restrict__ aggh)
{
    int wave = threadIdx.x >> 6;
    int lane = threadIdx.x & 63;
    int n = blockIdx.x * 4 + wave;
    if (n >= N) return;
    int ja = lane, jb = lane + 64;
    float w1a = (ja < F1) ? W1[ja] : 0.0f;
    float b1a = (ja < F1) ? b1[ja] : 0.0f;
    float w1b = (jb < F1) ? W1[jb] : 0.0f;
    float b1b = (jb < F1) ? b1[jb] : 0.0f;
    float d0 = dinv[n];
    float a0 = aggx[n];
    float accA = siluf(fmaf(a0, w1a, b1a)) * (d0 * d0);
    float accB = siluf(fmaf(a0, w1b, b1b)) * (d0 * d0);
    int beg = off[n], end = off[n + 1];
    for (int t = beg; t < end; t += 64) {
        int cnt = min(64, end - t);
        float sa = 0.0f, sw = 0.0f;
        if (lane < cnt) {
            int s = nbr[t + lane];
            sa = aggx[s];
            sw = dinv[s] * d0;
        }
        for (int i = 0; i < cnt; ++i) {
            float ai = __shfl(sa, i);
            float wi = __shfl(sw, i);
            accA += wi * siluf(fmaf(ai, w1a, b1a));
            accB += wi * siluf(fmaf(ai, w1b, b1b));
        }
    }
    if (ja < F1) aggh[(size_t)n * F1 + ja] = accA;
    if (jb < F1) aggh[(size_t)n * F1 + jb] = accB;
}

// Layer-2 aggregation as a pure gather of materialized h1 rows.
__global__ __launch_bounds__(256) void k_aggh_gather(
    const int* __restrict__ off, const int* __restrict__ nbr,
    const float* __restrict__ h1, const float* __restrict__ dinv,
    int N, float* __restrict__ aggh)
{
    int wave = threadIdx.x >> 6;
    int lane = threadIdx.x & 63;
    int n = blockIdx.x * 4 + wave;
    if (n >= N) return;
    const float2* h1f2 = (const float2*)h1;
    float d0 = dinv[n];
    bool act = lane < (F1 / 2);
    float accx = 0.0f, accy = 0.0f;
    if (act) {
        float2 v = h1f2[(size_t)n * (F1 / 2) + lane];
        accx = v.x * d0 * d0;
        accy = v.y * d0 * d0;
    }
    int beg = off[n], end = off[n + 1];
    for (int t = beg; t < end; t += 64) {
        int cnt = min(64, end - t);
        int sn = 0; float sw = 0.0f;
        if (lane < cnt) {
            sn = nbr[t + lane];
            sw = dinv[sn] * d0;
        }
        int i = 0;
        for (; i + 1 < cnt; i += 2) {
            int   s0 = __shfl(sn, i),     s1 = __shfl(sn, i + 1);
            float w0 = __shfl(sw, i),     w1 = __shfl(sw, i + 1);
            if (act) {
                float2 v0 = h1f2[(size_t)s0 * (F1 / 2) + lane];
                float2 v1 = h1f2[(size_t)s1 * (F1 / 2) + lane];
                accx = fmaf(w0, v0.x, accx); accy = fmaf(w0, v0.y, accy);
                accx = fmaf(w1, v1.x, accx); accy = fmaf(w1, v1.y, accy);
            }
        }
        if (i < cnt) {
            int   s0 = __shfl(sn, i);
            float w0 = __shfl(sw, i);
            if (act) {
                float2 v0 = h1f2[(size_t)s0 * (F1 / 2) + lane];
                accx = fmaf(w0, v0.x, accx); accy = fmaf(w0, v0.y, accy);
            }
        }
    }
    if (act) {
        float2 r; r.x = accx; r.y = accy;
        ((float2*)aggh)[(size_t)n * (F1 / 2) + lane] = r;
    }
}

__global__ void k_h1(const float* __restrict__ aggx, const float* __restrict__ W1,
                     const float* __restrict__ b1, int N, float* __restrict__ h1) {
    int idx = blockIdx.x * blockDim.x + threadIdx.x;
    int total = N * (F1 / 2);
    if (idx >= total) return;
    int n = idx / (F1 / 2);
    int p = idx % (F1 / 2);
    float a = aggx[n];
    float2 w = ((const float2*)W1)[p];
    float2 bb = ((const float2*)b1)[p];
    float2 r;
    r.x = siluf(fmaf(a, w.x, bb.x));
    r.y = siluf(fmaf(a, w.y, bb.y));
    ((float2*)h1)[idx] = r;
}

// Fused: h2 = silu(aggh @ W2 + b2), pooled[batch[n]] += h2 (double accumulation).
#define NPB 64
#define STAGE 8
__global__ __launch_bounds__(256) void k_h2_pool(
    const float* __restrict__ aggh, const float* __restrict__ W2, const float* __restrict__ b2,
    const int* __restrict__ batch, int N, double* __restrict__ pooled)
{
    __shared__ float sh[STAGE][F1];
    __shared__ int sbatch[NPB];
    int tid = threadIdx.x;
    int base = blockIdx.x * NPB;
    int m = tid;
    float w2c[F1];
    if (m < F2) {
        #pragma unroll
        for (int j = 0; j < F1; ++j) w2c[j] = W2[j * F2 + m];
    }
    float bb = (m < F2) ? b2[m] : 0.0f;
    if (tid < NPB && base + tid < N) sbatch[tid] = batch[base + tid];
    __syncthreads();
    double pl = 0.0;
    int gcur = -1;
    for (int t0 = 0; t0 < NPB; t0 += STAGE) {
        for (int idx = tid; idx < STAGE * F1; idx += 256) {
            int r = idx / F1, c = idx % F1;
            int n = base + t0 + r;
            sh[r][c] = (n < N) ? aggh[(size_t)n * F1 + c] : 0.0f;
        }
        __syncthreads();
        for (int r = 0; r < STAGE; ++r) {
            int n = base + t0 + r;
            if (n >= N) break;
            int g = sbatch[t0 + r];
            if (g != gcur) {
                if (gcur >= 0 && m < F2) atomicAdd(&pooled[(size_t)gcur * F2 + m], pl);
                pl = 0.0;
                gcur = g;
            }
            if (m < F2) {
                float acc = bb;
                #pragma unroll
                for (int j = 0; j < F1; ++j) acc = fmaf(sh[r][j], w2c[j], acc);
                pl += (double)siluf(acc);
            }
        }
        __syncthreads();
    }
    if (gcur >= 0 && m < F2) atomicAdd(&pooled[(size_t)gcur * F2 + m], pl);
}

// Head MLP: one block per graph, double precision.
__global__ __launch_bounds__(256) void k_head(
    const double* __restrict__ pooled, const int* __restrict__ counts,
    const float* __restrict__ Wl1, const float* __restrict__ bl1,
    const float* __restrict__ Wl2, const float* __restrict__ bl2,
    float* __restrict__ out)
{
    int g = blockIdx.x;
    int tid = threadIdx.x;
    __shared__ double sp[F2];
    __shared__ double red[256];
    double icnt = 1.0 / (double)max(counts[g], 1);
    for (int m = tid; m < F2; m += 256) sp[m] = pooled[(size_t)g * F2 + m] * icnt;
    __syncthreads();
    double part = 0.0;
    if (tid < 100) {
        double acc = (double)bl1[tid];
        #pragma unroll 4
        for (int m = 0; m < F2; ++m) acc += sp[m] * (double)Wl1[m * 100 + tid];
        double t1 = acc / (1.0 + exp(-acc));
        part = t1 * (double)Wl2[tid];
    }
    red[tid] = part;
    __syncthreads();
    for (int s = 128; s > 0; s >>= 1) {
        if (tid < s) red[tid] += red[tid + s];
        __syncthreads();
    }
    if (tid == 0) out[g] = (float)(red[0] + (double)bl2[0]);
}

extern "C" void kernel_launch(void* const* d_in, const int* in_sizes, int n_in,
                              void* d_out, int out_size, void* d_ws, size_t ws_size,
                              hipStream_t stream)
{
    const float* x   = (const float*)d_in[0];
    const int*   src = (const int*)d_in[1];
    const int*   dst = (const int*)d_in[2];
    const int*   batch = (const int*)d_in[3];
    const float* W1  = (const float*)d_in[4];
    const float* b1  = (const float*)d_in[5];
    const float* W2  = (const float*)d_in[6];
    const float* b2  = (const float*)d_in[7];
    const float* Wl1 = (const float*)d_in[8];
    const float* bl1 = (const float*)d_in[9];
    const float* Wl2 = (const float*)d_in[10];
    const float* bl2 = (const float*)d_in[11];
    int N = in_sizes[0];
    int E = in_sizes[1];
    int G = out_size;
    float* out = (float*)d_out;

    char* ws = (char*)d_ws;
    size_t o = 0;
    auto alloc = [&](size_t bytes) -> void* {
        o = (o + 255) & ~(size_t)255;
        void* p = ws + o;
        o += bytes;
        return p;
    };
    int nscan = (N + SCHUNK - 1) / SCHUNK;
    int nbk = (N + BW - 1) / BW;
    int*    deg    = (int*)alloc((size_t)N * 4);
    int*    cursor = (int*)alloc((size_t)N * 4);
    int*    off    = (int*)alloc((size_t)(N + 1) * 4);
    int*    nbr    = (int*)alloc((size_t)E * 4);
    float*  dinv   = (float*)alloc((size_t)N * 4);
    float*  aggx   = (float*)alloc((size_t)N * 4);
    float*  aggh   = (float*)alloc((size_t)N * F1 * 4);
    double* pooled = (double*)alloc((size_t)G * F2 * 8);
    int*    counts = (int*)alloc((size_t)G * 4);
    int*    starts = (int*)alloc((size_t)(G + 1) * 4);
    int*    partials = (int*)alloc((size_t)nscan * 4);
    int*    bcnt   = (int*)alloc((size_t)nbk * 4);
    int*    bbase  = (int*)alloc((size_t)(nbk + 1) * 4);
    int*    bcur   = (int*)alloc((size_t)nbk * 4);
    // gated large buffers
    o = (o + 255) & ~(size_t)255;
    float* h1 = (float*)(ws + o);
    bool use_h1 = (o + (size_t)N * F1 * 4) <= ws_size;
    size_t o2 = o + (use_h1 ? (size_t)N * F1 * 4 : 0);
    o2 = (o2 + 255) & ~(size_t)255;
    unsigned long long* pairs = (unsigned long long*)(ws + o2);
    bool use_bucket = use_h1 && ((o2 + (size_t)E * 8) <= ws_size);

    hipMemsetAsync(pooled, 0, (size_t)G * F2 * 8, stream);

    int tE = (E + 255) / 256;
    int tN = (N + 255) / 256;
    k_batch_bounds<<<1, 128, 0, stream>>>(batch, N, G, starts, counts);

    if (use_bucket) {
        hipMemsetAsync(bcnt, 0, (size_t)nbk * 4, stream);
        k_bucket_count<<<240, 256, nbk * 4, stream>>>(dst, E, nbk, bcnt);
        k_bucket_scan<<<1, 256, 0, stream>>>(bcnt, nbk, E, bbase, bcur);
        k_bucket_scatter<<<240, 256, 0, stream>>>(src, dst, E, nbk, bcur, bbase, pairs);
        k_bucket_deg<<<nbk, 512, 0, stream>>>(pairs, bbase, N, deg, dinv);
        k_scan_partial<<<nscan, 256, 0, stream>>>(deg, N, partials);
        k_scan_blocks<<<1, 1024, 0, stream>>>(partials, nscan);
        k_scan_final<<<nscan, 256, 0, stream>>>(deg, N, partials, off);
        k_bucket_fill_h1<<<nbk, 512, 0, stream>>>(pairs, bbase, off, x, dinv, W1, b1, N, nbr, h1);
        k_aggh_gather<<<(N + 3) / 4, 256, 0, stream>>>(off, nbr, h1, dinv, N, aggh);
    } else {
        hipMemsetAsync(deg, 0, (size_t)N * 4, stream);
        hipMemsetAsync(cursor, 0, (size_t)N * 4, stream);
        k_count_deg<<<tE, 256, 0, stream>>>(dst, E, deg);
        k_dinv_self<<<tN, 256, 0, stream>>>(deg, x, N, dinv, aggx);
        k_scan_partial<<<nscan, 256, 0, stream>>>(deg, N, partials);
        k_scan_blocks<<<1, 1024, 0, stream>>>(partials, nscan);
        k_scan_final<<<nscan, 256, 0, stream>>>(deg, N, partials, off);
        k_fill_agg<<<tE, 256, 0, stream>>>(src, dst, E, off, cursor, nbr, x, dinv, aggx);
        if (use_h1) {
            int th1 = (N * (F1 / 2) + 255) / 256;
            k_h1<<<th1, 256, 0, stream>>>(aggx, W1, b1, N, h1);
            k_aggh_gather<<<(N + 3) / 4, 256, 0, stream>>>(off, nbr, h1, dinv, N, aggh);
        } else {
            k_aggh<<<(N + 3) / 4, 256, 0, stream>>>(off, nbr, aggx, dinv, W1, b1, N, aggh);
        }
    }
    k_h2_pool<<<(N + NPB - 1) / NPB, 256, 0, stream>>>(aggh, W2, b2, batch, N, pooled);
    k_head<<<G, 256, 0, stream>>>(pooled, counts, Wl1, bl1, Wl2, bl2, out);
}